// Round 3
// baseline (212.684 us; speedup 1.0000x reference)
//
#include <hip/hip_runtime.h>

// VMD (Variational Mode Decomposition) for x: (16, 8192, 4) f32.
// B=16, C=4, T=8192, T2=16384, K=4, ALPHA=2000, TAU=0, 20 iterations.
// TAU=0 => lam == 0 forever. Negative half stays 0 => iterate on 8192 bins.
//
// R3: actually kill the spill. R2's __launch_bounds__(1024,4) only sets a MIN
// waves/EU bound; allocator still chose 64 VGPRs (8-wave target) and spilled
// ~20 floats/thread to scratch (L2-resident: FETCH 5.3MB/WRITE 19.4MB vs
// 2/16.8 ideal, VALUBusy 13%). amdgpu_waves_per_eu(4,4) pins min=max=4 ->
// VGPR budget 128. Also drop fr[8] array (recompute: f0 + u*0.0625f).

#define N2        16384
#define HALF      8192
#define LOGN      14
#define NTHREADS  1024
#define KMODES    4
#define NITERS    20
#define ALPHA_F   2000.0f
#define TWO_PI    6.28318530717958647692f

__device__ __forceinline__ unsigned bitrev14(unsigned x) { return __brev(x) >> 18; }

// ---------------------------------------------------------------------------
// Kernel 1: per-channel forward FFT of mirror-extended signal + 20 VMD iters.
// One block per channel (ch = b*4 + c), 1024 threads, 8 bins/thread.
// LDS 128KB => 1 block/CU => exactly 4 waves/EU; pin it so VGPR cap = 128.
// ---------------------------------------------------------------------------
__global__
__attribute__((amdgpu_flat_work_group_size(NTHREADS, NTHREADS),
               amdgpu_waves_per_eu(4, 4)))
void vmd_forward_iter(
    const float* __restrict__ x, float2* __restrict__ ws_u,
    float* __restrict__ ws_omega)
{
    __shared__ float2 A[N2];   // 128 KB (gfx950: 160 KB LDS/WG)
    const int tid = threadIdx.x;
    const int ch  = blockIdx.x;          // b*4 + c
    const int b   = ch >> 2, c = ch & 3;
    const float* xb = x + (size_t)b * 8192 * 4 + c;   // x[b, t, c], stride 4 in t

    // Mirror-extend: f[0:4096]=x[4095..0], f[4096:12288]=x[0..8191],
    // f[12288:16384]=x[8191..4096]
    for (int i = tid; i < N2; i += NTHREADS) {
        int t;
        if (i < 4096)       t = 4095 - i;
        else if (i < 12288) t = i - 4096;
        else                t = 20479 - i;
        A[i] = make_float2(xb[(size_t)t * 4], 0.0f);
    }
    __syncthreads();

    // Forward FFT: radix-2 DIF in place; position p ends up holding X[bitrev(p)].
    for (int s = 0; s < LOGN; ++s) {
        const int   half    = (N2 >> 1) >> s;           // 8192 .. 1
        const float inv_len = (float)(1 << s) / (float)N2;  // 1/len
        #pragma unroll
        for (int u = 0; u < 8; ++u) {
            int t   = tid + u * NTHREADS;               // butterfly id 0..8191
            int j   = t & (half - 1);
            int blk = t >> (13 - s);
            int i0  = blk * (half << 1) + j;
            int i1  = i0 + half;
            float2 a  = A[i0];
            float2 bb = A[i1];
            float dx = a.x - bb.x, dy = a.y - bb.y;
            float ang = -TWO_PI * ((float)j * inv_len);
            float sn, cs;
            __sincosf(ang, &sn, &cs);                   // w = e^{-2*pi*i*j/len}
            A[i0] = make_float2(a.x + bb.x, a.y + bb.y);
            A[i1] = make_float2(dx * cs - dy * sn, dx * sn + dy * cs);
        }
        __syncthreads();
    }

    // Read my 8 positive bins j = tid + u*1024 (F[j] sits at bitrev14(j)).
    // R = F - S with S=0 initially, so R starts as F.
    float Rx[8], Ry[8];
    #pragma unroll
    for (int u = 0; u < 8; ++u) {
        int j = tid + u * NTHREADS;
        float2 f = A[bitrev14((unsigned)j)];
        Rx[u] = f.x; Ry[u] = f.y;
    }
    __syncthreads();   // LDS now reusable as reduction scratch

    float Ux[KMODES][8], Uy[KMODES][8];
    #pragma unroll
    for (int u = 0; u < 8; ++u) {
        #pragma unroll
        for (int k = 0; k < KMODES; ++k) { Ux[k][u] = 0.f; Uy[k][u] = 0.f; }
    }
    const float f0 = (float)tid * (1.0f / (float)N2);   // fr[u] = f0 + u/16
    float omg[KMODES] = {0.0f, 0.125f, 0.25f, 0.375f};  // 0.5*k/K

    float* red = (float*)A;   // [16 waves][8] partials + [128..131] omega bcast

    for (int it = 0; it < NITERS; ++it) {
        float num[KMODES], den[KMODES];
        #pragma unroll
        for (int k = 0; k < KMODES; ++k) {
            float nk = 0.f, dk = 0.f;
            const float ok = omg[k];
            #pragma unroll
            for (int u = 0; u < 8; ++u) {
                float fru = f0 + (float)u * 0.0625f;
                float d   = fru - ok;
                float dnm = fmaf(ALPHA_F * d, d, 1.0f);
                float rcp = __builtin_amdgcn_rcpf(dnm);
                // numerator = F - (S - U_k) = R + U_k
                float nr = Rx[u] + Ux[k][u];
                float ni = Ry[u] + Uy[k][u];
                float ur = nr * rcp, ui = ni * rcp;
                // R' = num - U_new
                Rx[u] = nr - ur;
                Ry[u] = ni - ui;
                Ux[k][u] = ur; Uy[k][u] = ui;
                float p = fmaf(ur, ur, ui * ui);
                nk = fmaf(fru, p, nk);
                dk += p;
            }
            num[k] = nk; den[k] = dk;
        }
        // Batched block reduction of 8 scalars (num[4], den[4]).
        #pragma unroll
        for (int off = 32; off >= 1; off >>= 1) {
            #pragma unroll
            for (int m = 0; m < KMODES; ++m) {
                num[m] += __shfl_down(num[m], off);
                den[m] += __shfl_down(den[m], off);
            }
        }
        const int lane = tid & 63, wid = tid >> 6;
        if (lane == 0) {
            #pragma unroll
            for (int m = 0; m < KMODES; ++m) {
                red[wid * 8 + m]     = num[m];
                red[wid * 8 + 4 + m] = den[m];
            }
        }
        __syncthreads();
        if (tid < 16) {
            float v[8];
            #pragma unroll
            for (int m = 0; m < 8; ++m) v[m] = red[tid * 8 + m];
            #pragma unroll
            for (int off = 8; off >= 1; off >>= 1) {
                #pragma unroll
                for (int m = 0; m < 8; ++m) v[m] += __shfl_down(v[m], off);
            }
            if (tid == 0) {
                #pragma unroll
                for (int m = 0; m < KMODES; ++m) red[128 + m] = v[m] / v[4 + m];
            }
        }
        __syncthreads();
        #pragma unroll
        for (int m = 0; m < KMODES; ++m) omg[m] = red[128 + m];
        // no barrier needed: next writes touch red[0..127] only (disjoint)
    }

    // Write final positive-half u_hat and omega.
    #pragma unroll
    for (int k = 0; k < KMODES; ++k) {
        float2* dst = ws_u + (size_t)(ch * KMODES + k) * HALF;
        #pragma unroll
        for (int u = 0; u < 8; ++u)
            dst[tid + u * NTHREADS] = make_float2(Ux[k][u], Uy[k][u]);
    }
    if (tid < KMODES) ws_omega[ch * KMODES + tid] = omg[tid];
}

// ---------------------------------------------------------------------------
// Kernel 2: per (channel, mode) inverse FFT; keep real part of middle T samples.
// Spectrum in natural FFT order (derived from full/ifftshift in reference):
//   G[0] = conj(p[0]); G[j] = p[j] (1<=j<8192); G[8192] = conj(p[8191]);
//   G[16384-j] = conj(p[j]) (1<=j<8192).
// ---------------------------------------------------------------------------
__global__ __launch_bounds__(NTHREADS) void vmd_inverse(
    const float2* __restrict__ ws_u, float* __restrict__ out)
{
    __shared__ float2 A[N2];
    const int tid = threadIdx.x;
    const int bid = blockIdx.x;             // ch*4 + k
    const float2* pos = ws_u + (size_t)bid * HALF;

    for (int i = tid; i < HALF; i += NTHREADS) {
        float2 p = pos[i];
        if (i == 0) {
            A[0] = make_float2(p.x, -p.y);
        } else {
            A[i]      = p;
            A[N2 - i] = make_float2(p.x, -p.y);
        }
        if (i == HALF - 1) A[HALF] = make_float2(p.x, -p.y);
    }
    __syncthreads();

    // Inverse FFT: radix-2 DIF with e^{+i...}; output bit-reversed; scale 1/N.
    for (int s = 0; s < LOGN; ++s) {
        const int   half    = (N2 >> 1) >> s;
        const float inv_len = (float)(1 << s) / (float)N2;
        #pragma unroll
        for (int u = 0; u < 8; ++u) {
            int t   = tid + u * NTHREADS;
            int j   = t & (half - 1);
            int blk = t >> (13 - s);
            int i0  = blk * (half << 1) + j;
            int i1  = i0 + half;
            float2 a  = A[i0];
            float2 bb = A[i1];
            float dx = a.x - bb.x, dy = a.y - bb.y;
            float ang = TWO_PI * ((float)j * inv_len);
            float sn, cs;
            __sincosf(ang, &sn, &cs);
            A[i0] = make_float2(a.x + bb.x, a.y + bb.y);
            A[i1] = make_float2(dx * cs - dy * sn, dx * sn + dy * cs);
        }
        __syncthreads();
    }

    // u[b,k,t,c] = Re(ifft)[4096 + t] ; out index ((b*4+k)*8192 + t)*4 + c
    const int ch = bid >> 2, k = bid & 3;
    const int b  = ch >> 2,  c = ch & 3;
    float* outp = out + (size_t)(b * 4 + k) * 8192 * 4 + c;
    for (int i = tid; i < HALF; i += NTHREADS) {
        int n = 4096 + i;
        float v = A[bitrev14((unsigned)n)].x * (1.0f / (float)N2);
        outp[(size_t)i * 4] = v;
    }
}

// ---------------------------------------------------------------------------
// Kernel 3: omega_b[b,k] = mean_c omega[b,c,k]
// ---------------------------------------------------------------------------
__global__ void omega_mean(const float* __restrict__ ws_omega,
                           float* __restrict__ out_omega)
{
    int i = threadIdx.x;                 // b*4 + k, 64 total
    if (i < 64) {
        int b = i >> 2, k = i & 3;
        float s = 0.f;
        #pragma unroll
        for (int c = 0; c < 4; ++c) s += ws_omega[(b * 4 + c) * 4 + k];
        out_omega[i] = 0.25f * s;
    }
}

extern "C" void kernel_launch(void* const* d_in, const int* in_sizes, int n_in,
                              void* d_out, int out_size, void* d_ws, size_t ws_size,
                              hipStream_t stream)
{
    (void)in_sizes; (void)n_in; (void)out_size; (void)ws_size;
    const float* x = (const float*)d_in[0];
    float* out = (float*)d_out;

    float2* ws_u     = (float2*)d_ws;  // 64 ch * 4 modes * 8192 float2 = 16 MB
    float*  ws_omega = (float*)((char*)d_ws + (size_t)64 * 4 * HALF * sizeof(float2));

    vmd_forward_iter<<<64, NTHREADS, 0, stream>>>(x, ws_u, ws_omega);
    vmd_inverse<<<256, NTHREADS, 0, stream>>>(ws_u, out);
    omega_mean<<<1, 64, 0, stream>>>(ws_omega, out + 2097152);
}

// Round 5
// 205.164 us; speedup vs baseline: 1.0367x; 1.0367x over previous
//
#include <hip/hip_runtime.h>

// VMD (Variational Mode Decomposition) for x: (16, 8192, 4) f32.
// B=16, C=4, T=8192, T2=16384, K=4, ALPHA=2000, TAU=0, 20 iterations.
// TAU=0 => lam == 0 forever. Negative half stays 0 => iterate on 8192 bins.
//
// R5 == R4 with compile fix (cvt_pkrtz returns __fp16 ext-vector, not _Float16).
//  - U stored as packed f16 (half2 per complex): state 80 -> 48 floats, fits
//    the allocator's 64-VGPR choice (R2/R3 spilled ~20 floats to L2 scratch).
//  - Wave reduction via DPP (row_shr + row_bcast, VALU pipe) instead of 48
//    ds_swizzle per thread-iter.
//  - FFT twiddles via raw v_sin/v_cos in revolutions (no range reduction).

#define N2        16384
#define HALF      8192
#define LOGN      14
#define NTHREADS  1024
#define KMODES    4
#define NITERS    20
#define ALPHA_F   2000.0f

typedef __fp16 half2_t __attribute__((ext_vector_type(2)));

__device__ __forceinline__ unsigned bitrev14(unsigned x) { return __brev(x) >> 18; }

__device__ __forceinline__ unsigned pack_h2(float a, float b) {
    half2_t h = __builtin_amdgcn_cvt_pkrtz(a, b);   // v_cvt_pkrtz_f16_f32
    return __builtin_bit_cast(unsigned, h);
}
__device__ __forceinline__ float2 unpack_h2(unsigned u) {
    half2_t h = __builtin_bit_cast(half2_t, u);
    return make_float2((float)h.x, (float)h.y);
}

template <int CTRL>
__device__ __forceinline__ float dpp_add_step(float v) {
    int r = __builtin_amdgcn_update_dpp(0, __float_as_int(v), CTRL, 0xf, 0xf, true);
    return v + __int_as_float(r);
}
// Full-wave (64-lane) sum; result valid in lane 63.
__device__ __forceinline__ float wave64_sum(float v) {
    v = dpp_add_step<0x111>(v);   // row_shr:1
    v = dpp_add_step<0x112>(v);   // row_shr:2
    v = dpp_add_step<0x114>(v);   // row_shr:4
    v = dpp_add_step<0x118>(v);   // row_shr:8  -> lane15 of each row = row sum
    v = dpp_add_step<0x142>(v);   // row_bcast:15
    v = dpp_add_step<0x143>(v);   // row_bcast:31 -> lane63 = wave sum
    return v;
}

// ---------------------------------------------------------------------------
// Kernel 1: per-channel forward FFT of mirror-extended signal + 20 VMD iters.
// One block per channel (ch = b*4 + c), 1024 threads, 8 bins/thread.
// ---------------------------------------------------------------------------
__global__ __launch_bounds__(NTHREADS) void vmd_forward_iter(
    const float* __restrict__ x, float2* __restrict__ ws_u,
    float* __restrict__ ws_omega)
{
    __shared__ float2 A[N2];   // 128 KB (gfx950: 160 KB LDS/WG)
    const int tid = threadIdx.x;
    const int ch  = blockIdx.x;          // b*4 + c
    const int b   = ch >> 2, c = ch & 3;
    const float* xb = x + (size_t)b * 8192 * 4 + c;   // x[b, t, c], stride 4 in t

    // Mirror-extend: f[0:4096]=x[4095..0], f[4096:12288]=x[0..8191],
    // f[12288:16384]=x[8191..4096]
    for (int i = tid; i < N2; i += NTHREADS) {
        int t;
        if (i < 4096)       t = 4095 - i;
        else if (i < 12288) t = i - 4096;
        else                t = 20479 - i;
        A[i] = make_float2(xb[(size_t)t * 4], 0.0f);
    }
    __syncthreads();

    // Forward FFT: radix-2 DIF in place; position p ends up holding X[bitrev(p)].
    for (int s = 0; s < LOGN; ++s) {
        const int   half    = (N2 >> 1) >> s;           // 8192 .. 1
        const float inv_len = (float)(1 << s) / (float)N2;  // 1/len
        #pragma unroll
        for (int u = 0; u < 8; ++u) {
            int t   = tid + u * NTHREADS;               // butterfly id 0..8191
            int j   = t & (half - 1);
            int blk = t >> (13 - s);
            int i0  = blk * (half << 1) + j;
            int i1  = i0 + half;
            float2 a  = A[i0];
            float2 bb = A[i1];
            float dx = a.x - bb.x, dy = a.y - bb.y;
            float rev = (float)j * inv_len;             // angle in revolutions
            float cs = __builtin_amdgcn_cosf(rev);      // cos(2*pi*rev)
            float sn = -__builtin_amdgcn_sinf(rev);     // sin(-2*pi*rev)
            A[i0] = make_float2(a.x + bb.x, a.y + bb.y);
            A[i1] = make_float2(dx * cs - dy * sn, dx * sn + dy * cs);
        }
        __syncthreads();
    }

    // Read my 8 positive bins j = tid + u*1024 (F[j] sits at bitrev14(j)).
    // R = F - S with S=0 initially, so R starts as F.
    float Rx[8], Ry[8];
    #pragma unroll
    for (int u = 0; u < 8; ++u) {
        int j = tid + u * NTHREADS;
        float2 f = A[bitrev14((unsigned)j)];
        Rx[u] = f.x; Ry[u] = f.y;
    }
    __syncthreads();   // LDS now reusable as reduction scratch

    unsigned Up[KMODES][8];    // U_k packed as (f16 re, f16 im)
    #pragma unroll
    for (int u = 0; u < 8; ++u)
        #pragma unroll
        for (int k = 0; k < KMODES; ++k) Up[k][u] = 0u;

    const float f0 = (float)tid * (1.0f / (float)N2);   // fr[u] = f0 + u/16
    float omg[KMODES] = {0.0f, 0.125f, 0.25f, 0.375f};  // 0.5*k/K

    float* red = (float*)A;   // [16 waves][8] partials; [128..135] totals

    const int lane = tid & 63, wid = tid >> 6;

    for (int it = 0; it < NITERS; ++it) {
        float num[KMODES], den[KMODES];
        #pragma unroll
        for (int k = 0; k < KMODES; ++k) {
            float nk = 0.f, dk = 0.f;
            const float ok = omg[k];
            #pragma unroll
            for (int u = 0; u < 8; ++u) {
                float fru = f0 + (float)u * 0.0625f;
                float d   = fru - ok;
                float dnm = fmaf(ALPHA_F * d, d, 1.0f);
                float rcp = __builtin_amdgcn_rcpf(dnm);
                float2 uo = unpack_h2(Up[k][u]);
                // numerator = F - (S - U_k) = R + U_k
                float nr = Rx[u] + uo.x;
                float ni = Ry[u] + uo.y;
                float ur = nr * rcp, ui = ni * rcp;
                // R' = num - U_new
                Rx[u] = nr - ur;
                Ry[u] = ni - ui;
                Up[k][u] = pack_h2(ur, ui);
                float p = fmaf(ur, ur, ui * ui);
                nk = fmaf(fru, p, nk);
                dk += p;
            }
            num[k] = nk; den[k] = dk;
        }
        // Stage 1: DPP wave sums (VALU pipe, no LDS), lane63 writes partials.
        #pragma unroll
        for (int m = 0; m < KMODES; ++m) {
            num[m] = wave64_sum(num[m]);
            den[m] = wave64_sum(den[m]);
        }
        if (lane == 63) {
            float4* r4 = (float4*)&red[wid * 8];
            r4[0] = make_float4(num[0], num[1], num[2], num[3]);
            r4[1] = make_float4(den[0], den[1], den[2], den[3]);
        }
        __syncthreads();
        // Stage 2: 8 threads sum the 16 wave-partials of their scalar.
        if (tid < 8) {
            float s = 0.f;
            #pragma unroll
            for (int w = 0; w < 16; ++w) s += red[w * 8 + tid];
            red[128 + tid] = s;
        }
        __syncthreads();
        {
            const float4 nv = *(const float4*)&red[128];
            const float4 dv = *(const float4*)&red[132];
            omg[0] = nv.x * __builtin_amdgcn_rcpf(dv.x);
            omg[1] = nv.y * __builtin_amdgcn_rcpf(dv.y);
            omg[2] = nv.z * __builtin_amdgcn_rcpf(dv.z);
            omg[3] = nv.w * __builtin_amdgcn_rcpf(dv.w);
        }
        // next iteration writes red[0..127] (disjoint from 128..135) before
        // its first barrier, and red[128..135] only after it — safe.
    }

    // Write final positive-half u_hat and omega.
    #pragma unroll
    for (int k = 0; k < KMODES; ++k) {
        float2* dst = ws_u + (size_t)(ch * KMODES + k) * HALF;
        #pragma unroll
        for (int u = 0; u < 8; ++u) {
            float2 uv = unpack_h2(Up[k][u]);
            dst[tid + u * NTHREADS] = uv;
        }
    }
    if (tid < KMODES) ws_omega[ch * KMODES + tid] = omg[tid];
}

// ---------------------------------------------------------------------------
// Kernel 2: per (channel, mode) inverse FFT; keep real part of middle T samples.
// Spectrum in natural FFT order (derived from full/ifftshift in reference):
//   G[0] = conj(p[0]); G[j] = p[j] (1<=j<8192); G[8192] = conj(p[8191]);
//   G[16384-j] = conj(p[j]) (1<=j<8192).
// ---------------------------------------------------------------------------
__global__ __launch_bounds__(NTHREADS) void vmd_inverse(
    const float2* __restrict__ ws_u, float* __restrict__ out)
{
    __shared__ float2 A[N2];
    const int tid = threadIdx.x;
    const int bid = blockIdx.x;             // ch*4 + k
    const float2* pos = ws_u + (size_t)bid * HALF;

    for (int i = tid; i < HALF; i += NTHREADS) {
        float2 p = pos[i];
        if (i == 0) {
            A[0] = make_float2(p.x, -p.y);
        } else {
            A[i]      = p;
            A[N2 - i] = make_float2(p.x, -p.y);
        }
        if (i == HALF - 1) A[HALF] = make_float2(p.x, -p.y);
    }
    __syncthreads();

    // Inverse FFT: radix-2 DIF with e^{+i...}; output bit-reversed; scale 1/N.
    for (int s = 0; s < LOGN; ++s) {
        const int   half    = (N2 >> 1) >> s;
        const float inv_len = (float)(1 << s) / (float)N2;
        #pragma unroll
        for (int u = 0; u < 8; ++u) {
            int t   = tid + u * NTHREADS;
            int j   = t & (half - 1);
            int blk = t >> (13 - s);
            int i0  = blk * (half << 1) + j;
            int i1  = i0 + half;
            float2 a  = A[i0];
            float2 bb = A[i1];
            float dx = a.x - bb.x, dy = a.y - bb.y;
            float rev = (float)j * inv_len;
            float cs = __builtin_amdgcn_cosf(rev);
            float sn = __builtin_amdgcn_sinf(rev);      // +2*pi for inverse
            A[i0] = make_float2(a.x + bb.x, a.y + bb.y);
            A[i1] = make_float2(dx * cs - dy * sn, dx * sn + dy * cs);
        }
        __syncthreads();
    }

    // u[b,k,t,c] = Re(ifft)[4096 + t] ; out index ((b*4+k)*8192 + t)*4 + c
    const int ch = bid >> 2, k = bid & 3;
    const int b  = ch >> 2,  c = ch & 3;
    float* outp = out + (size_t)(b * 4 + k) * 8192 * 4 + c;
    for (int i = tid; i < HALF; i += NTHREADS) {
        int n = 4096 + i;
        float v = A[bitrev14((unsigned)n)].x * (1.0f / (float)N2);
        outp[(size_t)i * 4] = v;
    }
}

// ---------------------------------------------------------------------------
// Kernel 3: omega_b[b,k] = mean_c omega[b,c,k]
// ---------------------------------------------------------------------------
__global__ void omega_mean(const float* __restrict__ ws_omega,
                           float* __restrict__ out_omega)
{
    int i = threadIdx.x;                 // b*4 + k, 64 total
    if (i < 64) {
        int b = i >> 2, k = i & 3;
        float s = 0.f;
        #pragma unroll
        for (int c = 0; c < 4; ++c) s += ws_omega[(b * 4 + c) * 4 + k];
        out_omega[i] = 0.25f * s;
    }
}

extern "C" void kernel_launch(void* const* d_in, const int* in_sizes, int n_in,
                              void* d_out, int out_size, void* d_ws, size_t ws_size,
                              hipStream_t stream)
{
    (void)in_sizes; (void)n_in; (void)out_size; (void)ws_size;
    const float* x = (const float*)d_in[0];
    float* out = (float*)d_out;

    float2* ws_u     = (float2*)d_ws;  // 64 ch * 4 modes * 8192 float2 = 16 MB
    float*  ws_omega = (float*)((char*)d_ws + (size_t)64 * 4 * HALF * sizeof(float2));

    vmd_forward_iter<<<64, NTHREADS, 0, stream>>>(x, ws_u, ws_omega);
    vmd_inverse<<<256, NTHREADS, 0, stream>>>(ws_u, out);
    omega_mean<<<1, 64, 0, stream>>>(ws_omega, out + 2097152);
}

// Round 6
// 193.945 us; speedup vs baseline: 1.0966x; 1.0578x over previous
//
#include <hip/hip_runtime.h>

// VMD (Variational Mode Decomposition) for x: (16, 8192, 4) f32.
// B=16, C=4, T=8192, T2=16384, K=4, ALPHA=2000, TAU=0, 20 iterations.
// TAU=0 => lam == 0. Negative half stays 0 => iterate on 8192 positive bins.
//
// R6: halve FFT issue cost with real-signal half-size transforms.
//  - Forward: f real => z[m]=f[2m]+i*f[2m+1], 8192-pt FFT (13 stages, 4
//    bf/thread) + untangle to positive bins F[0..8191].
//  - Inverse: G Hermitian => Z[j]=E+i*W*O, 8192-pt iFFT, x[2m]=Re, x[2m+1]=Im.
//  - Iteration: packed f32 (ext_vector(2) -> v_pk_*_f32).
//  - U stays packed f16 (fits 64-VGPR allocation; R5 killed the spill).

#define HALF      8192
#define NH        8192        // half-size FFT length
#define LOGH      13
#define NTHREADS  1024
#define KMODES    4
#define NITERS    20
#define ALPHA_F   2000.0f

typedef __fp16 half2_t __attribute__((ext_vector_type(2)));
typedef float  v2f     __attribute__((ext_vector_type(2)));

__device__ __forceinline__ unsigned bitrev13(unsigned x) { return __brev(x) >> 19; }

__device__ __forceinline__ unsigned pack_h2(float a, float b) {
    half2_t h = __builtin_amdgcn_cvt_pkrtz(a, b);   // v_cvt_pkrtz_f16_f32
    return __builtin_bit_cast(unsigned, h);
}
__device__ __forceinline__ v2f unpack_h2(unsigned u) {
    half2_t h = __builtin_bit_cast(half2_t, u);
    v2f r; r.x = (float)h.x; r.y = (float)h.y; return r;
}

template <int CTRL>
__device__ __forceinline__ float dpp_add_step(float v) {
    int r = __builtin_amdgcn_update_dpp(0, __float_as_int(v), CTRL, 0xf, 0xf, true);
    return v + __int_as_float(r);
}
// Full-wave (64-lane) sum; result valid in lane 63.
__device__ __forceinline__ float wave64_sum(float v) {
    v = dpp_add_step<0x111>(v);   // row_shr:1
    v = dpp_add_step<0x112>(v);   // row_shr:2
    v = dpp_add_step<0x114>(v);   // row_shr:4
    v = dpp_add_step<0x118>(v);   // row_shr:8
    v = dpp_add_step<0x142>(v);   // row_bcast:15
    v = dpp_add_step<0x143>(v);   // row_bcast:31 -> lane63 = wave sum
    return v;
}

// time-domain mirror extension: f[i], i in [0,16384)
__device__ __forceinline__ int mirror_t(int i) {
    if (i < 4096)       return 4095 - i;
    else if (i < 12288) return i - 4096;
    else                return 20479 - i;
}

// ---------------------------------------------------------------------------
// Kernel 1: per-channel real-FFT (half-size) + 20 VMD iterations.
// One block per channel (ch = b*4 + c), 1024 threads.
// ---------------------------------------------------------------------------
__global__ __launch_bounds__(NTHREADS) void vmd_forward_iter(
    const float* __restrict__ x, float2* __restrict__ ws_u,
    float* __restrict__ ws_omega)
{
    __shared__ float2 A[NH];   // 64 KB
    const int tid = threadIdx.x;
    const int ch  = blockIdx.x;          // b*4 + c
    const int b   = ch >> 2, c = ch & 3;
    const float* xb = x + (size_t)b * 8192 * 4 + c;   // x[b, t, c], stride 4

    // z[m] = f[2m] + i f[2m+1]
    for (int m = tid; m < NH; m += NTHREADS) {
        float re = xb[(size_t)mirror_t(2 * m) * 4];
        float im = xb[(size_t)mirror_t(2 * m + 1) * 4];
        A[m] = make_float2(re, im);
    }
    __syncthreads();

    // 8192-pt forward FFT, radix-2 DIF; position p holds Z[bitrev13(p)].
    for (int s = 0; s < LOGH; ++s) {
        const int   half    = (NH >> 1) >> s;           // 4096 .. 1
        const float inv_len = (float)(1 << s) / (float)NH;
        #pragma unroll
        for (int u = 0; u < 4; ++u) {
            int t   = tid + u * NTHREADS;               // butterfly id 0..4095
            int j   = t & (half - 1);
            int blk = t >> (12 - s);
            int i0  = blk * (half << 1) + j;
            int i1  = i0 + half;
            float2 a  = A[i0];
            float2 bb = A[i1];
            float dx = a.x - bb.x, dy = a.y - bb.y;
            float rev = (float)j * inv_len;             // angle in revolutions
            float cs = __builtin_amdgcn_cosf(rev);
            float sn = -__builtin_amdgcn_sinf(rev);     // e^{-2*pi*i*rev}
            A[i0] = make_float2(a.x + bb.x, a.y + bb.y);
            A[i1] = make_float2(dx * cs - dy * sn, dx * sn + dy * cs);
        }
        __syncthreads();
    }

    // Untangle: F[j] = E[j] + w*O[j], w = e^{-2*pi*i*j/16384}, j=0..8191.
    // E = (Z[j]+conj(Z[-j]))/2, O = -i*(Z[j]-conj(Z[-j]))/2.
    v2f R[8];
    #pragma unroll
    for (int u = 0; u < 8; ++u) {
        int j  = tid + u * NTHREADS;
        float2 z1 = A[bitrev13((unsigned)j)];
        float2 z2 = A[bitrev13((unsigned)((NH - j) & (NH - 1)))];
        float ex = 0.5f * (z1.x + z2.x);
        float ey = 0.5f * (z1.y - z2.y);
        float dx = 0.5f * (z1.x - z2.x);
        float dy = 0.5f * (z1.y + z2.y);
        // O = (dy, -dx)
        float rev = (float)j * (1.0f / 16384.0f);
        float wr = __builtin_amdgcn_cosf(rev);
        float wi = -__builtin_amdgcn_sinf(rev);
        R[u].x = ex + wr * dy + wi * dx;    // E + (wr*Ox - wi*Oy)
        R[u].y = ey + wi * dy - wr * dx;    // E + (wr*Oy + wi*Ox)
    }
    __syncthreads();   // LDS now reusable as reduction scratch

    unsigned Up[KMODES][8];    // U_k packed as (f16 re, f16 im)
    #pragma unroll
    for (int u = 0; u < 8; ++u)
        #pragma unroll
        for (int k = 0; k < KMODES; ++k) Up[k][u] = 0u;

    const float f0 = (float)tid * (1.0f / 16384.0f);    // fr[u] = f0 + u/16
    float omg[KMODES] = {0.0f, 0.125f, 0.25f, 0.375f};  // 0.5*k/K

    float* red = (float*)A;   // [16 waves][8] partials; [128..135] totals
    const int lane = tid & 63, wid = tid >> 6;

    for (int it = 0; it < NITERS; ++it) {
        float num[KMODES], den[KMODES];
        #pragma unroll
        for (int k = 0; k < KMODES; ++k) {
            float nk = 0.f, dk = 0.f;
            const float ok = omg[k];
            #pragma unroll
            for (int u = 0; u < 8; ++u) {
                float fru = f0 + (float)u * 0.0625f;
                float d   = fru - ok;
                float dnm = fmaf(ALPHA_F * d, d, 1.0f);
                float rcp = __builtin_amdgcn_rcpf(dnm);
                v2f uo  = unpack_h2(Up[k][u]);
                v2f nm  = R[u] + uo;          // v_pk_add_f32
                v2f un  = nm * rcp;           // v_pk_mul_f32 (splat)
                R[u]    = nm - un;            // v_pk_add_f32 (neg)
                Up[k][u] = pack_h2(un.x, un.y);
                float p = fmaf(un.x, un.x, un.y * un.y);
                nk = fmaf(fru, p, nk);
                dk += p;
            }
            num[k] = nk; den[k] = dk;
        }
        // Stage 1: DPP wave sums, lane63 writes partials.
        #pragma unroll
        for (int m = 0; m < KMODES; ++m) {
            num[m] = wave64_sum(num[m]);
            den[m] = wave64_sum(den[m]);
        }
        if (lane == 63) {
            float4* r4 = (float4*)&red[wid * 8];
            r4[0] = make_float4(num[0], num[1], num[2], num[3]);
            r4[1] = make_float4(den[0], den[1], den[2], den[3]);
        }
        __syncthreads();
        // Stage 2: 8 threads sum the 16 wave-partials of their scalar.
        if (tid < 8) {
            float s = 0.f;
            #pragma unroll
            for (int w = 0; w < 16; ++w) s += red[w * 8 + tid];
            red[128 + tid] = s;
        }
        __syncthreads();
        {
            const float4 nv = *(const float4*)&red[128];
            const float4 dv = *(const float4*)&red[132];
            omg[0] = nv.x * __builtin_amdgcn_rcpf(dv.x);
            omg[1] = nv.y * __builtin_amdgcn_rcpf(dv.y);
            omg[2] = nv.z * __builtin_amdgcn_rcpf(dv.z);
            omg[3] = nv.w * __builtin_amdgcn_rcpf(dv.w);
        }
        // next iter writes red[0..127] (disjoint from 128..135) — safe.
    }

    // Write final positive-half u_hat and omega.
    #pragma unroll
    for (int k = 0; k < KMODES; ++k) {
        float2* dst = ws_u + (size_t)(ch * KMODES + k) * HALF;
        #pragma unroll
        for (int u = 0; u < 8; ++u) {
            v2f uv = unpack_h2(Up[k][u]);
            dst[tid + u * NTHREADS] = make_float2(uv.x, uv.y);
        }
    }
    if (tid < KMODES) ws_omega[ch * KMODES + tid] = omg[tid];
}

// ---------------------------------------------------------------------------
// Kernel 2: per (channel,mode) half-size real iFFT; middle T real samples.
// Full spectrum (verified R1): G[0]=conj(p[0]); G[j]=p[j] (1<=j<8192);
// G[8192]=conj(p[8191]); G[16384-j]=conj(p[j]).
// Half-size: E[j]=(G[j]+G[j+8192])/2, D=(G[j]-G[j+8192])/2,
//   O[j]=D*e^{+2*pi*i*j/16384}, Z=E+i*O, z=iFFT_8192(Z),
//   x[2m]=Re z[m], x[2m+1]=Im z[m].
// ---------------------------------------------------------------------------
__global__ __launch_bounds__(NTHREADS) void vmd_inverse(
    const float2* __restrict__ ws_u, float* __restrict__ out)
{
    __shared__ float2 A[NH];   // 64 KB
    const int tid = threadIdx.x;
    const int bid = blockIdx.x;             // ch*4 + k
    const float2* pos = ws_u + (size_t)bid * HALF;

    for (int j = tid; j < NH; j += NTHREADS) {
        float2 gj, gh;
        if (j == 0) {
            float2 p0 = pos[0], pl = pos[HALF - 1];
            gj = make_float2(p0.x, -p0.y);       // G[0]    = conj(p[0])
            gh = make_float2(pl.x, -pl.y);       // G[8192] = conj(p[8191])
        } else {
            gj = pos[j];                          // G[j]
            float2 q = pos[HALF - j];             // G[j+8192] = conj(p[8192-j])
            gh = make_float2(q.x, -q.y);
        }
        float ex = 0.5f * (gj.x + gh.x), ey = 0.5f * (gj.y + gh.y);
        float dx = 0.5f * (gj.x - gh.x), dy = 0.5f * (gj.y - gh.y);
        float rev = (float)j * (1.0f / 16384.0f);
        float wr = __builtin_amdgcn_cosf(rev);
        float wi = __builtin_amdgcn_sinf(rev);    // e^{+2*pi*i*rev}
        float ox = dx * wr - dy * wi;
        float oy = dx * wi + dy * wr;
        A[j] = make_float2(ex - oy, ey + ox);     // Z = E + i*O
    }
    __syncthreads();

    // 8192-pt inverse FFT (e^{+i}), radix-2 DIF; output bit-reversed.
    for (int s = 0; s < LOGH; ++s) {
        const int   half    = (NH >> 1) >> s;
        const float inv_len = (float)(1 << s) / (float)NH;
        #pragma unroll
        for (int u = 0; u < 4; ++u) {
            int t   = tid + u * NTHREADS;
            int j   = t & (half - 1);
            int blk = t >> (12 - s);
            int i0  = blk * (half << 1) + j;
            int i1  = i0 + half;
            float2 a  = A[i0];
            float2 bb = A[i1];
            float dx = a.x - bb.x, dy = a.y - bb.y;
            float rev = (float)j * inv_len;
            float cs = __builtin_amdgcn_cosf(rev);
            float sn = __builtin_amdgcn_sinf(rev);
            A[i0] = make_float2(a.x + bb.x, a.y + bb.y);
            A[i1] = make_float2(dx * cs - dy * sn, dx * sn + dy * cs);
        }
        __syncthreads();
    }

    // Keep n in [4096,12288): m in [2048,6144). x[2m]=Re z, x[2m+1]=Im z.
    const int ch = bid >> 2, k = bid & 3;
    const int b  = ch >> 2,  c = ch & 3;
    float* outp = out + (size_t)(b * 4 + k) * 8192 * 4 + c;
    for (int m = 2048 + tid; m < 6144; m += NTHREADS) {
        float2 z = A[bitrev13((unsigned)m)];
        int t0 = 2 * m - 4096;
        outp[(size_t)t0 * 4]       = z.x * (1.0f / 8192.0f);
        outp[(size_t)(t0 + 1) * 4] = z.y * (1.0f / 8192.0f);
    }
}

// ---------------------------------------------------------------------------
// Kernel 3: omega_b[b,k] = mean_c omega[b,c,k]
// ---------------------------------------------------------------------------
__global__ void omega_mean(const float* __restrict__ ws_omega,
                           float* __restrict__ out_omega)
{
    int i = threadIdx.x;                 // b*4 + k, 64 total
    if (i < 64) {
        int b = i >> 2, k = i & 3;
        float s = 0.f;
        #pragma unroll
        for (int c = 0; c < 4; ++c) s += ws_omega[(b * 4 + c) * 4 + k];
        out_omega[i] = 0.25f * s;
    }
}

extern "C" void kernel_launch(void* const* d_in, const int* in_sizes, int n_in,
                              void* d_out, int out_size, void* d_ws, size_t ws_size,
                              hipStream_t stream)
{
    (void)in_sizes; (void)n_in; (void)out_size; (void)ws_size;
    const float* x = (const float*)d_in[0];
    float* out = (float*)d_out;

    float2* ws_u     = (float2*)d_ws;  // 64 ch * 4 modes * 8192 float2 = 16 MB
    float*  ws_omega = (float*)((char*)d_ws + (size_t)64 * 4 * HALF * sizeof(float2));

    vmd_forward_iter<<<64, NTHREADS, 0, stream>>>(x, ws_u, ws_omega);
    vmd_inverse<<<256, NTHREADS, 0, stream>>>(ws_u, out);
    omega_mean<<<1, 64, 0, stream>>>(ws_omega, out + 2097152);
}

// Round 7
// 178.407 us; speedup vs baseline: 1.1921x; 1.0871x over previous
//
#include <hip/hip_runtime.h>

// VMD (Variational Mode Decomposition) for x: (16, 8192, 4) f32.
// B=16, C=4, T=8192, T2=16384, K=4, ALPHA=2000, TAU=0, 20 iterations.
// TAU=0 => lam == 0. Negative half stays 0 => iterate on 8192 positive bins.
//
// R7: attack LDS-conflict + barrier-drain cost in both FFTs.
//  - LDS padding P(i)=i+(i>>4): float2 bank period is 16 elements; padding
//    breaks all power-of-2 strides (R6 conflicts: 1.6M cycles).
//  - Radix-4 passes (2 radix-2 stages fused in registers): 13 stages -> 7
//    LDS round-trips/barriers, half LDS traffic, 1 sincos per 4 points.
//    Arithmetic identical to 2 radix-2 stages => layout stays bit-reversed.
//  - Iteration loop unchanged from R6 (packed f32 + f16 U + DPP reduction).

#define HALF      8192
#define NH        8192        // half-size FFT length
#define LOGH      13
#define NTHREADS  1024
#define KMODES    4
#define NITERS    20
#define ALPHA_F   2000.0f

typedef __fp16 half2_t __attribute__((ext_vector_type(2)));
typedef float  v2f     __attribute__((ext_vector_type(2)));

__device__ __forceinline__ unsigned bitrev13(unsigned x) { return __brev(x) >> 19; }
__device__ __forceinline__ int pidx(int i) { return i + (i >> 4); }   // LDS pad

__device__ __forceinline__ unsigned pack_h2(float a, float b) {
    half2_t h = __builtin_amdgcn_cvt_pkrtz(a, b);   // v_cvt_pkrtz_f16_f32
    return __builtin_bit_cast(unsigned, h);
}
__device__ __forceinline__ v2f unpack_h2(unsigned u) {
    half2_t h = __builtin_bit_cast(half2_t, u);
    v2f r; r.x = (float)h.x; r.y = (float)h.y; return r;
}

template <int CTRL>
__device__ __forceinline__ float dpp_add_step(float v) {
    int r = __builtin_amdgcn_update_dpp(0, __float_as_int(v), CTRL, 0xf, 0xf, true);
    return v + __int_as_float(r);
}
// Full-wave (64-lane) sum; result valid in lane 63.
__device__ __forceinline__ float wave64_sum(float v) {
    v = dpp_add_step<0x111>(v);   // row_shr:1
    v = dpp_add_step<0x112>(v);   // row_shr:2
    v = dpp_add_step<0x114>(v);   // row_shr:4
    v = dpp_add_step<0x118>(v);   // row_shr:8
    v = dpp_add_step<0x142>(v);   // row_bcast:15
    v = dpp_add_step<0x143>(v);   // row_bcast:31 -> lane63 = wave sum
    return v;
}

__device__ __forceinline__ float2 cmul(float2 a, float wr, float wi) {
    return make_float2(a.x * wr - a.y * wi, a.x * wi + a.y * wr);
}

// One radix-4 pass = two fused radix-2 DIF stages (h = 2*hh, L = 2h).
// INV=false: e^{-i} twiddles; INV=true: e^{+i}.
template <bool INV>
__device__ __forceinline__ void fft_pass4(float2* A, int tid, int s) {
    const int   log2hh = 11 - 2 * s;
    const int   hh     = 1 << log2hh;                       // h/2
    const float inv2h  = (float)(1 << (2 * s)) * (1.0f / 8192.0f);  // 1/(2h)
    #pragma unroll
    for (int u = 0; u < 2; ++u) {
        int gid = tid + u * NTHREADS;            // group id, 2048 total
        int j   = gid & (hh - 1);
        int blk = gid >> log2hh;
        int i0  = (blk << (log2hh + 2)) + j;     // blk*2h + j
        int i1  = i0 + hh;
        int i2  = i0 + 2 * hh;
        int i3  = i0 + 3 * hh;
        float2 a = A[pidx(i0)], b = A[pidx(i1)];
        float2 c = A[pidx(i2)], d = A[pidx(i3)];
        float rev = (float)j * inv2h;
        float w1r = __builtin_amdgcn_cosf(rev);
        float w1i = INV ?  __builtin_amdgcn_sinf(rev)
                        : -__builtin_amdgcn_sinf(rev);
        // stage L=2h: (a,c) w/ W1; (b,d) w/ W2 = (-/+)i*W1
        float2 ac = make_float2(a.x - c.x, a.y - c.y);
        float2 bd = make_float2(b.x - d.x, b.y - d.y);
        float2 t0 = make_float2(a.x + c.x, a.y + c.y);
        float2 t2 = make_float2(b.x + d.x, b.y + d.y);
        float2 t1 = cmul(ac, w1r, w1i);
        float2 t3;
        if (INV) { // W2 = +i*W1 = (-w1i, w1r)
            t3 = make_float2(-bd.x * w1i - bd.y * w1r, bd.x * w1r - bd.y * w1i);
        } else {   // W2 = -i*W1 = (w1i, -w1r)
            t3 = make_float2( bd.x * w1i + bd.y * w1r, bd.y * w1i - bd.x * w1r);
        }
        // stage L=h: twiddle V = W1^2
        float vr = w1r * w1r - w1i * w1i;
        float vi = 2.0f * w1r * w1i;
        float2 s0 = make_float2(t0.x + t2.x, t0.y + t2.y);
        float2 s1 = cmul(make_float2(t0.x - t2.x, t0.y - t2.y), vr, vi);
        float2 s2 = make_float2(t1.x + t3.x, t1.y + t3.y);
        float2 s3 = cmul(make_float2(t1.x - t3.x, t1.y - t3.y), vr, vi);
        A[pidx(i0)] = s0;
        A[pidx(i1)] = s1;
        A[pidx(i2)] = s2;
        A[pidx(i3)] = s3;
    }
}

// Final radix-2 stage (h=1): pairs (2t, 2t+1), twiddle = 1.
__device__ __forceinline__ void fft_last2(float2* A, int tid) {
    #pragma unroll
    for (int u = 0; u < 4; ++u) {
        int t  = tid + u * NTHREADS;
        int i0 = 2 * t, i1 = 2 * t + 1;
        float2 a = A[pidx(i0)], b = A[pidx(i1)];
        A[pidx(i0)] = make_float2(a.x + b.x, a.y + b.y);
        A[pidx(i1)] = make_float2(a.x - b.x, a.y - b.y);
    }
}

// time-domain mirror extension: f[i], i in [0,16384)
__device__ __forceinline__ int mirror_t(int i) {
    if (i < 4096)       return 4095 - i;
    else if (i < 12288) return i - 4096;
    else                return 20479 - i;
}

// ---------------------------------------------------------------------------
// Kernel 1: per-channel real-FFT (half-size, radix-4) + 20 VMD iterations.
// One block per channel (ch = b*4 + c), 1024 threads.
// ---------------------------------------------------------------------------
__global__ __launch_bounds__(NTHREADS) void vmd_forward_iter(
    const float* __restrict__ x, float2* __restrict__ ws_u,
    float* __restrict__ ws_omega)
{
    __shared__ float2 A[NH + (NH >> 4)];   // padded, ~68 KB
    const int tid = threadIdx.x;
    const int ch  = blockIdx.x;          // b*4 + c
    const int b   = ch >> 2, c = ch & 3;
    const float* xb = x + (size_t)b * 8192 * 4 + c;   // x[b, t, c], stride 4

    // z[m] = f[2m] + i f[2m+1]
    for (int m = tid; m < NH; m += NTHREADS) {
        float re = xb[(size_t)mirror_t(2 * m) * 4];
        float im = xb[(size_t)mirror_t(2 * m + 1) * 4];
        A[pidx(m)] = make_float2(re, im);
    }
    __syncthreads();

    // 8192-pt forward FFT: 6 radix-4 passes + 1 radix-2 stage; bit-reversed out.
    for (int s = 0; s < 6; ++s) {
        fft_pass4<false>(A, tid, s);
        __syncthreads();
    }
    fft_last2(A, tid);
    __syncthreads();

    // Untangle: F[j] = E[j] + w*O[j], w = e^{-2*pi*i*j/16384}, j=0..8191.
    v2f R[8];
    #pragma unroll
    for (int u = 0; u < 8; ++u) {
        int j  = tid + u * NTHREADS;
        float2 z1 = A[pidx((int)bitrev13((unsigned)j))];
        float2 z2 = A[pidx((int)bitrev13((unsigned)((NH - j) & (NH - 1))))];
        float ex = 0.5f * (z1.x + z2.x);
        float ey = 0.5f * (z1.y - z2.y);
        float dx = 0.5f * (z1.x - z2.x);
        float dy = 0.5f * (z1.y + z2.y);
        // O = (dy, -dx)
        float rev = (float)j * (1.0f / 16384.0f);
        float wr = __builtin_amdgcn_cosf(rev);
        float wi = -__builtin_amdgcn_sinf(rev);
        R[u].x = ex + wr * dy + wi * dx;
        R[u].y = ey + wi * dy - wr * dx;
    }
    __syncthreads();   // LDS now reusable as reduction scratch

    unsigned Up[KMODES][8];    // U_k packed as (f16 re, f16 im)
    #pragma unroll
    for (int u = 0; u < 8; ++u)
        #pragma unroll
        for (int k = 0; k < KMODES; ++k) Up[k][u] = 0u;

    const float f0 = (float)tid * (1.0f / 16384.0f);    // fr[u] = f0 + u/16
    float omg[KMODES] = {0.0f, 0.125f, 0.25f, 0.375f};  // 0.5*k/K

    float* red = (float*)A;   // [16 waves][8] partials; [128..135] totals
    const int lane = tid & 63, wid = tid >> 6;

    for (int it = 0; it < NITERS; ++it) {
        float num[KMODES], den[KMODES];
        #pragma unroll
        for (int k = 0; k < KMODES; ++k) {
            float nk = 0.f, dk = 0.f;
            const float ok = omg[k];
            #pragma unroll
            for (int u = 0; u < 8; ++u) {
                float fru = f0 + (float)u * 0.0625f;
                float d   = fru - ok;
                float dnm = fmaf(ALPHA_F * d, d, 1.0f);
                float rcp = __builtin_amdgcn_rcpf(dnm);
                v2f uo  = unpack_h2(Up[k][u]);
                v2f nm  = R[u] + uo;          // v_pk_add_f32
                v2f un  = nm * rcp;           // v_pk_mul_f32 (splat)
                R[u]    = nm - un;            // v_pk_add_f32
                Up[k][u] = pack_h2(un.x, un.y);
                float p = fmaf(un.x, un.x, un.y * un.y);
                nk = fmaf(fru, p, nk);
                dk += p;
            }
            num[k] = nk; den[k] = dk;
        }
        // Stage 1: DPP wave sums, lane63 writes partials.
        #pragma unroll
        for (int m = 0; m < KMODES; ++m) {
            num[m] = wave64_sum(num[m]);
            den[m] = wave64_sum(den[m]);
        }
        if (lane == 63) {
            float4* r4 = (float4*)&red[wid * 8];
            r4[0] = make_float4(num[0], num[1], num[2], num[3]);
            r4[1] = make_float4(den[0], den[1], den[2], den[3]);
        }
        __syncthreads();
        // Stage 2: 8 threads sum the 16 wave-partials of their scalar.
        if (tid < 8) {
            float s = 0.f;
            #pragma unroll
            for (int w = 0; w < 16; ++w) s += red[w * 8 + tid];
            red[128 + tid] = s;
        }
        __syncthreads();
        {
            const float4 nv = *(const float4*)&red[128];
            const float4 dv = *(const float4*)&red[132];
            omg[0] = nv.x * __builtin_amdgcn_rcpf(dv.x);
            omg[1] = nv.y * __builtin_amdgcn_rcpf(dv.y);
            omg[2] = nv.z * __builtin_amdgcn_rcpf(dv.z);
            omg[3] = nv.w * __builtin_amdgcn_rcpf(dv.w);
        }
        // next iter writes red[0..127] (disjoint from 128..135) — safe.
    }

    // Write final positive-half u_hat and omega.
    #pragma unroll
    for (int k = 0; k < KMODES; ++k) {
        float2* dst = ws_u + (size_t)(ch * KMODES + k) * HALF;
        #pragma unroll
        for (int u = 0; u < 8; ++u) {
            v2f uv = unpack_h2(Up[k][u]);
            dst[tid + u * NTHREADS] = make_float2(uv.x, uv.y);
        }
    }
    if (tid < KMODES) ws_omega[ch * KMODES + tid] = omg[tid];
}

// ---------------------------------------------------------------------------
// Kernel 2: per (channel,mode) half-size real iFFT; middle T real samples.
// Full spectrum (verified R1): G[0]=conj(p[0]); G[j]=p[j] (1<=j<8192);
// G[8192]=conj(p[8191]); G[16384-j]=conj(p[j]).
// Half-size: E[j]=(G[j]+G[j+8192])/2, D=(G[j]-G[j+8192])/2,
//   O[j]=D*e^{+2*pi*i*j/16384}, Z=E+i*O, z=iFFT_8192(Z),
//   x[2m]=Re z[m], x[2m+1]=Im z[m].
// ---------------------------------------------------------------------------
__global__ __launch_bounds__(NTHREADS) void vmd_inverse(
    const float2* __restrict__ ws_u, float* __restrict__ out)
{
    __shared__ float2 A[NH + (NH >> 4)];
    const int tid = threadIdx.x;
    const int bid = blockIdx.x;             // ch*4 + k
    const float2* pos = ws_u + (size_t)bid * HALF;

    for (int j = tid; j < NH; j += NTHREADS) {
        float2 gj, gh;
        if (j == 0) {
            float2 p0 = pos[0], pl = pos[HALF - 1];
            gj = make_float2(p0.x, -p0.y);       // G[0]    = conj(p[0])
            gh = make_float2(pl.x, -pl.y);       // G[8192] = conj(p[8191])
        } else {
            gj = pos[j];                          // G[j]
            float2 q = pos[HALF - j];             // G[j+8192] = conj(p[8192-j])
            gh = make_float2(q.x, -q.y);
        }
        float ex = 0.5f * (gj.x + gh.x), ey = 0.5f * (gj.y + gh.y);
        float dx = 0.5f * (gj.x - gh.x), dy = 0.5f * (gj.y - gh.y);
        float rev = (float)j * (1.0f / 16384.0f);
        float wr = __builtin_amdgcn_cosf(rev);
        float wi = __builtin_amdgcn_sinf(rev);    // e^{+2*pi*i*rev}
        float ox = dx * wr - dy * wi;
        float oy = dx * wi + dy * wr;
        A[pidx(j)] = make_float2(ex - oy, ey + ox);   // Z = E + i*O
    }
    __syncthreads();

    // 8192-pt inverse FFT: 6 radix-4 passes + 1 radix-2 stage; bit-reversed out.
    for (int s = 0; s < 6; ++s) {
        fft_pass4<true>(A, tid, s);
        __syncthreads();
    }
    fft_last2(A, tid);
    __syncthreads();

    // Keep n in [4096,12288): m in [2048,6144). x[2m]=Re z, x[2m+1]=Im z.
    const int ch = bid >> 2, k = bid & 3;
    const int b  = ch >> 2,  c = ch & 3;
    float* outp = out + (size_t)(b * 4 + k) * 8192 * 4 + c;
    for (int m = 2048 + tid; m < 6144; m += NTHREADS) {
        float2 z = A[pidx((int)bitrev13((unsigned)m))];
        int t0 = 2 * m - 4096;
        outp[(size_t)t0 * 4]       = z.x * (1.0f / 8192.0f);
        outp[(size_t)(t0 + 1) * 4] = z.y * (1.0f / 8192.0f);
    }
}

// ---------------------------------------------------------------------------
// Kernel 3: omega_b[b,k] = mean_c omega[b,c,k]
// ---------------------------------------------------------------------------
__global__ void omega_mean(const float* __restrict__ ws_omega,
                           float* __restrict__ out_omega)
{
    int i = threadIdx.x;                 // b*4 + k, 64 total
    if (i < 64) {
        int b = i >> 2, k = i & 3;
        float s = 0.f;
        #pragma unroll
        for (int c = 0; c < 4; ++c) s += ws_omega[(b * 4 + c) * 4 + k];
        out_omega[i] = 0.25f * s;
    }
}

extern "C" void kernel_launch(void* const* d_in, const int* in_sizes, int n_in,
                              void* d_out, int out_size, void* d_ws, size_t ws_size,
                              hipStream_t stream)
{
    (void)in_sizes; (void)n_in; (void)out_size; (void)ws_size;
    const float* x = (const float*)d_in[0];
    float* out = (float*)d_out;

    float2* ws_u     = (float2*)d_ws;  // 64 ch * 4 modes * 8192 float2 = 16 MB
    float*  ws_omega = (float*)((char*)d_ws + (size_t)64 * 4 * HALF * sizeof(float2));

    vmd_forward_iter<<<64, NTHREADS, 0, stream>>>(x, ws_u, ws_omega);
    vmd_inverse<<<256, NTHREADS, 0, stream>>>(ws_u, out);
    omega_mean<<<1, 64, 0, stream>>>(ws_omega, out + 2097152);
}